// Round 8
// baseline (148.545 us; speedup 1.0000x reference)
//
#include <hip/hip_runtime.h>

typedef float f32x4 __attribute__((ext_vector_type(4)));

#define MFMA8(a, b, c) __builtin_amdgcn_mfma_f32_16x16x32_fp8_fp8((long)(a), (long)(b), (c), 0, 0, 0)

__device__ __forceinline__ unsigned char f2fp8(float v) {
    int pk = __builtin_amdgcn_cvt_pk_fp8_f32(v, v, 0, false);
    return (unsigned char)(pk & 0xff);
}
__device__ __forceinline__ long packrow8(const float* p) {
    f32x4 a = *(const f32x4*)(p);
    f32x4 b = *(const f32x4*)(p + 4);
    int lo = __builtin_amdgcn_cvt_pk_fp8_f32(a.x, a.y, 0, false);
    lo = __builtin_amdgcn_cvt_pk_fp8_f32(a.z, a.w, lo, true);
    int hi = __builtin_amdgcn_cvt_pk_fp8_f32(b.x, b.y, 0, false);
    hi = __builtin_amdgcn_cvt_pk_fp8_f32(b.z, b.w, hi, true);
    return (long)(((unsigned long)(unsigned int)hi << 32) | (unsigned int)lo);
}
__device__ __forceinline__ int pack4(const float* p) {
    int v = __builtin_amdgcn_cvt_pk_fp8_f32(p[0], p[1], 0, false);
    return __builtin_amdgcn_cvt_pk_fp8_f32(p[2], p[3], v, true);
}
// pack 8 register floats -> 8 fp8 bytes (same cvt_pk rounding as f2fp8 path)
__device__ __forceinline__ long pack8v(const float* p) {
    int lo = __builtin_amdgcn_cvt_pk_fp8_f32(p[0], p[1], 0, false);
    lo = __builtin_amdgcn_cvt_pk_fp8_f32(p[2], p[3], lo, true);
    int hi = __builtin_amdgcn_cvt_pk_fp8_f32(p[4], p[5], 0, false);
    hi = __builtin_amdgcn_cvt_pk_fp8_f32(p[6], p[7], hi, true);
    return (long)(((unsigned long)(unsigned int)hi << 32) | (unsigned int)lo);
}

// ---------------- Kernel 1 (fallback only): LayerNorm partial sums ----------------
__global__ __launch_bounds__(256) void k_ln_part(const float* __restrict__ x,
                                                 float* __restrict__ part) {
    const int chunk = blockIdx.x, b = blockIdx.y, t = threadIdx.x;
    const float4* p = (const float4*)(x + b * 262144 + chunk * 16384);
    float s = 0.f, ss = 0.f;
    #pragma unroll
    for (int r = 0; r < 16; ++r) {
        float4 v = p[r * 256 + t];
        s  += v.x + v.y + v.z + v.w;
        ss += v.x * v.x + v.y * v.y + v.z * v.z + v.w * v.w;
    }
    #pragma unroll
    for (int off = 32; off > 0; off >>= 1) {
        s  += __shfl_down(s, off);
        ss += __shfl_down(ss, off);
    }
    __shared__ float sm[8];
    int wv = t >> 6;
    if ((t & 63) == 0) { sm[wv * 2] = s; sm[wv * 2 + 1] = ss; }
    __syncthreads();
    if (t == 0) {
        float S  = sm[0] + sm[2] + sm[4] + sm[6];
        float SS = sm[1] + sm[3] + sm[5] + sm[7];
        part[(b * 16 + chunk) * 2]     = S;
        part[(b * 16 + chunk) * 2 + 1] = SS;
    }
}

// ---------------- Kernel 2 (fallback only): LayerNorm finalize ----------------
__global__ void k_ln_fin(const float* __restrict__ part, float* __restrict__ stats) {
    int t = threadIdx.x;
    if (t < 32) {
        float S = 0.f, SS = 0.f;
        for (int k = 0; k < 16; ++k) {
            S  += part[(t * 16 + k) * 2];
            SS += part[(t * 16 + k) * 2 + 1];
        }
        const float inv = 1.0f / 262144.0f;
        float mu  = S * inv;
        float var = SS * inv - mu * mu;
        stats[t * 2]     = mu;
        stats[t * 2 + 1] = rsqrtf(var + 1e-5f);
    }
}

// ---------------- Kernel A: conv + K/V build + LN partials + weight pack ----------------
// grid (16 mi-rows, 32 batches), 512 threads. K stored [b][m][64] XOR-SWIZZLED
// (col ^= (row&7)<<3, matching attn reads), V stored [b][d][256].
// r6 (kept): x read as dwordx4; conv = per-lane dot(float4,float4) + 2 shuffles.
// Block (0,0) additionally packs Wq/Wo to fp8.
__global__ __launch_bounds__(512) void k_kvb2(
    const float* __restrict__ x, const float* __restrict__ Wdw, const float* __restrict__ bdw,
    const float* __restrict__ Wk, const float* __restrict__ bk,
    const float* __restrict__ Wv, const float* __restrict__ bv,
    const float* __restrict__ Wq, const float* __restrict__ Wo,
    unsigned char* __restrict__ Kg, unsigned char* __restrict__ Vg,
    float* __restrict__ part, unsigned char* __restrict__ Wq8, unsigned char* __restrict__ Wo8)
{
    __shared__ __align__(16) unsigned char Y[16 * 72];
    __shared__ float sm[16];
    const int mi = blockIdx.x, b = blockIdx.y;
    const int t = threadIdx.x, w = t >> 6, lane = t & 63;
    const int quad = lane >> 4, l = lane & 15;
    const float* xb = x + b * 262144;

    // weight fp8 pre-pack, one block only (512 threads x 8 values each matrix)
    if ((mi | b) == 0) {
        float f[8];
        #pragma unroll
        for (int g = 0; g < 2; ++g) *(f32x4*)&f[g * 4] = *(const f32x4*)(Wq + t * 8 + g * 4);
        int2 o;
        o.x = pack4(f); o.y = pack4(f + 4);
        *(int2*)(Wq8 + t * 8) = o;
        #pragma unroll
        for (int g = 0; g < 2; ++g) *(f32x4*)&f[g * 4] = *(const f32x4*)(Wo + t * 8 + g * 4);
        o.x = pack4(f); o.y = pack4(f + 4);
        *(int2*)(Wo8 + t * 8) = o;
    }

    // lane mapping: r4 = image row within 4-row chunk, c4 = output col (float4 index)
    const int r4 = lane >> 4, c4 = lane & 15;
    float s = 0.f, ss = 0.f;
    #pragma unroll
    for (int ci = 0; ci < 8; ++ci) {
        int c = w * 8 + ci;
        f32x4 wd = *(const f32x4*)(Wdw + c * 16 + r4 * 4);
        f32x4 v  = *(const f32x4*)(xb + c * 4096 + mi * 256 + r4 * 64 + c4 * 4);
        s  += v.x + v.y + v.z + v.w;
        ss += v.x * v.x + v.y * v.y + v.z * v.z + v.w * v.w;
        float acc = v.x * wd.x;
        acc = fmaf(v.y, wd.y, acc);
        acc = fmaf(v.z, wd.z, acc);
        acc = fmaf(v.w, wd.w, acc);
        acc += __shfl_xor(acc, 16);   // sum rows 0<->1 (bit 4 of lane)
        acc += __shfl_xor(acc, 32);   // sum rows 0<->2 (bit 5 of lane)
        if (r4 == 0) Y[c4 * 72 + c] = f2fp8(acc + bdw[c]);
    }
    #pragma unroll
    for (int off = 32; off > 0; off >>= 1) {
        s  += __shfl_down(s, off);
        ss += __shfl_down(ss, off);
    }
    if (lane == 0) { sm[w * 2] = s; sm[w * 2 + 1] = ss; }
    __syncthreads();
    if (t == 0) {
        float S = 0.f, SS = 0.f;
        #pragma unroll
        for (int i = 0; i < 8; ++i) { S += sm[i * 2]; SS += sm[i * 2 + 1]; }
        part[(b * 16 + mi) * 2]     = S;
        part[(b * 16 + mi) * 2 + 1] = SS;
    }

    long ya0 = *(const long*)(Y + l * 72 + quad * 8);
    long ya1 = *(const long*)(Y + l * 72 + 32 + quad * 8);
    if (w < 4) {
        int e4 = w;
        long f0 = packrow8(Wk + (e4 * 16 + l) * 64 + quad * 8);
        long f1 = packrow8(Wk + (e4 * 16 + l) * 64 + 32 + quad * 8);
        float bb = bk[e4 * 16 + l];
        f32x4 c = { bb, bb, bb, bb };
        c = MFMA8(ya0, f0, c);
        c = MFMA8(ya1, f1, c);
        // swizzled K write: row = m-index, col ^= (row&7)<<3  (matches attn kb reads)
        unsigned char* kdB = Kg + b * 16384;
        int colk = e4 * 16 + l;
        #pragma unroll
        for (int r = 0; r < 4; ++r) {
            int row = mi * 16 + quad * 4 + r;
            kdB[row * 64 + (colk ^ ((row & 7) << 3))] = f2fp8(c[r]);
        }
    } else {
        int d4 = w - 4;
        long f0 = packrow8(Wv + (d4 * 16 + l) * 64 + quad * 8);
        long f1 = packrow8(Wv + (d4 * 16 + l) * 64 + 32 + quad * 8);
        f32x4 c = { bv[d4 * 16 + quad * 4 + 0], bv[d4 * 16 + quad * 4 + 1],
                    bv[d4 * 16 + quad * 4 + 2], bv[d4 * 16 + quad * 4 + 3] };
        c = MFMA8(f0, ya0, c);
        c = MFMA8(f1, ya1, c);
        unsigned char* vd = Vg + b * 16384 + (d4 * 16 + quad * 4) * 256 + mi * 16 + l;
        #pragma unroll
        for (int r = 0; r < 4; ++r) vd[r * 256] = f2fp8(c[r]);
    }
}

// ---------------- Kernel C: attention, 128-query tile, 16 waves, 2 blocks/CU ----------------
// mc-loop body byte-identical to the proven r0/r3/r5 path. Per-wave work unchanged
// (16 q-rows x 1 head); the block is WIDENED to 16 parallel waves (not serial tiles --
// r2's failure mode was serial). K/V staging, weight fragments, LN finalize amortized 2x.
// LDS: Kf 16384 @0 | Vt [64][272] 17408 @16384 | QF[128][72]/PS 16x640/TS overlay
//      10240 @33792 = 44032 B -> 2 blocks/CU x 1024 thr = 2048 = 32-wave/CU cap (same occ).
__global__ __launch_bounds__(1024, 8) void k_attn6(
    const float* __restrict__ x, const unsigned char* __restrict__ Wq8,
    const float* __restrict__ bq, const unsigned char* __restrict__ Wo8,
    const float* __restrict__ bo, const float* __restrict__ Bb,
    const float* __restrict__ part, const unsigned char* __restrict__ Kg,
    const unsigned char* __restrict__ Vg, float* __restrict__ outp)
{
    __shared__ __align__(16) long smem8[5504];   // 44032 B
    unsigned char* S = (unsigned char*)smem8;
    unsigned char* Kf = S;                 // [256][64] swizzled
    unsigned char* Vt = S + 16384;         // [64][272]
    unsigned char* QF = S + 33792;         // [128][72] (until qa read)
    unsigned char* TS = S + 33792;         // alias (after bar3)
    const int tile = blockIdx.x, b = blockIdx.y;
    const int t = threadIdx.x, w = t >> 6, lane = t & 63;
    const int quad = lane >> 4, l = lane & 15;
    unsigned char* PS = S + 33792 + w * 640;   // alias (mc-loop), 16 waves x 640
    const int n0 = tile * 128;
    const float* xb = x + b * 262144;
    const float SCALE = 0.17677669529663687f;

    // ---- LN finalize inline (uniform L2 loads) ----
    float Sp = 0.f, SSp = 0.f;
    #pragma unroll
    for (int k2 = 0; k2 < 16; ++k2) {
        Sp  += part[(b * 16 + k2) * 2];
        SSp += part[(b * 16 + k2) * 2 + 1];
    }
    const float invN = 1.0f / 262144.0f;
    const float mu = Sp * invN;
    const float rstd = rsqrtf(SSp * invN - mu * mu + 1e-5f);

    // ---- stage K (identity copy: Kg pre-swizzled) and V, once per 128-query block ----
    const unsigned char* Kgb = Kg + b * 16384;
    const unsigned char* Vgb = Vg + b * 16384;
    *(uint4*)(Kf + t * 16) = *(const uint4*)(Kgb + t * 16);
    {
        int d = t >> 4, e16 = (t & 15) * 16;
        *(uint4*)(Vt + d * 272 + e16) = *(const uint4*)(Vgb + d * 256 + e16);
    }

    // ---- weight fragments from pre-packed fp8 ----
    const int rtq = w >> 1, ct0 = (w & 1) * 2;   // rtq 0..7 (16-row chunks), ct0 in {0,2}
    long wqF[4], woF[4];
    float bqr[2], bor[2];
    #pragma unroll
    for (int i = 0; i < 2; ++i) {
        #pragma unroll
        for (int st = 0; st < 2; ++st) {
            wqF[i * 2 + st] = *(const long*)(Wq8 + ((ct0 + i) * 16 + l) * 64 + st * 32 + quad * 8);
            woF[i * 2 + st] = *(const long*)(Wo8 + ((ct0 + i) * 16 + l) * 64 + st * 32 + quad * 8);
        }
        bqr[i] = bq[(ct0 + i) * 16 + l];
        bor[i] = bo[(ct0 + i) * 16 + l];
    }

    // ---- Q A-fragment straight from global x (registers; no XS round trip) ----
    long xa0, xa1;
    {
        const float* xq = xb + n0 + rtq * 16 + l;
        float xn[8];
        #pragma unroll
        for (int j = 0; j < 8; ++j)
            xn[j] = (xq[(quad * 8 + j) * 4096] - mu) * rstd;
        xa0 = pack8v(xn);
        #pragma unroll
        for (int j = 0; j < 8; ++j)
            xn[j] = (xq[(32 + quad * 8 + j) * 4096] - mu) * rstd;
        xa1 = pack8v(xn);
    }
    // ---- Q-gen via MFMA -> QF fp8 (before bar1: overlaps K/V staging latency) ----
    #pragma unroll
    for (int i = 0; i < 2; ++i) {
        f32x4 c = { bqr[i], bqr[i], bqr[i], bqr[i] };
        c = MFMA8(xa0, wqF[i * 2 + 0], c);
        c = MFMA8(xa1, wqF[i * 2 + 1], c);
        unsigned char* qd = QF + (rtq * 16 + quad * 4) * 72 + (ct0 + i) * 16 + l;
        #pragma unroll
        for (int r = 0; r < 4; ++r) qd[r * 72] = f2fp8(c[r]);
    }
    __syncthreads();   // bar1: K/V staged + all QF written

    // ---- attention: wave = (h = w&1, nq = w>>1), 16 q-rows, 256 keys ----
    const int h = w & 1, nq = w >> 1;
    long qa = *(const long*)(QF + (nq * 16 + l) * 72 + h * 32 + quad * 8);
    __syncthreads();   // bar2: qa reads done -> PS may overwrite QF region

    f32x4 O0 = { 0, 0, 0, 0 }, O1 = { 0, 0, 0, 0 };
    float Lp[4] = { 0, 0, 0, 0 };
    const float* Bbase = Bb + h * 1048576 + (n0 + nq * 16 + quad * 4) * 256;

    // kb base: row = mt*16+l (row&7 = l&7), col = (h*32+quad*8) ^ ((l&7)<<3) -- loop-invariant
    const unsigned char* Kfl = Kf + l * 64 + ((h * 32 + quad * 8) ^ ((l & 7) << 3));

    // software-pipelined B loads: Bv holds biases for current mc (PROVEN r0 path)
    float Bv[2][4];
    #pragma unroll
    for (int sub = 0; sub < 2; ++sub)
        #pragma unroll
        for (int r = 0; r < 4; ++r)
            Bv[sub][r] = Bbase[r * 256 + sub * 16 + l];

    #pragma unroll 2
    for (int mc = 0; mc < 8; ++mc) {
        float Bn[2][4];
        if (mc < 7) {
            #pragma unroll
            for (int sub = 0; sub < 2; ++sub)
                #pragma unroll
                for (int r = 0; r < 4; ++r)
                    Bn[sub][r] = Bbase[r * 256 + (mc * 2 + 2 + sub) * 16 + l];
        }
        long kb0 = *(const long*)(Kfl + (mc * 2 + 0) * 1024);
        long kb1 = *(const long*)(Kfl + (mc * 2 + 1) * 1024);
        #pragma unroll
        for (int sub = 0; sub < 2; ++sub) {
            f32x4 sc = { 0, 0, 0, 0 };
            sc = MFMA8(qa, sub ? kb1 : kb0, sc);
            unsigned char* pw = PS + (quad * 4) * 40 + sub * 16 + l;
            #pragma unroll
            for (int r = 0; r < 4; ++r) {
                float p = __expf(fmaf(sc[r], SCALE, Bv[sub][r]));
                Lp[r] += p;
                pw[r * 40] = f2fp8(p);
            }
        }
        long pa  = *(const long*)(PS + l * 40 + quad * 8);
        long vb0 = *(const long*)(Vt + (h * 32 + l) * 272 + mc * 32 + quad * 8);
        long vb1 = *(const long*)(Vt + (h * 32 + 16 + l) * 272 + mc * 32 + quad * 8);
        O0 = MFMA8(pa, vb0, O0);
        O1 = MFMA8(pa, vb1, O1);
        #pragma unroll
        for (int sub = 0; sub < 2; ++sub)
            #pragma unroll
            for (int r = 0; r < 4; ++r)
                Bv[sub][r] = Bn[sub][r];
    }
    #pragma unroll
    for (int r = 0; r < 4; ++r) {
        #pragma unroll
        for (int d = 1; d < 16; d <<= 1) Lp[r] += __shfl_xor(Lp[r], d);
    }
    __syncthreads();   // bar3: all pa reads done -> PS region reusable as TS
    {
        unsigned char* td = TS + (nq * 16 + quad * 4) * 72 + h * 32 + l;
        #pragma unroll
        for (int r = 0; r < 4; ++r) {
            float inv = 1.0f / Lp[r];
            td[r * 72]      = f2fp8(O0[r] * inv);
            td[r * 72 + 16] = f2fp8(O1[r] * inv);
        }
    }
    __syncthreads();   // bar4: TS complete

    // ---- out-proj + bias + residual ----
    {
        long ta0 = *(const long*)(TS + (rtq * 16 + l) * 72 + quad * 8);
        long ta1 = *(const long*)(TS + (rtq * 16 + l) * 72 + 32 + quad * 8);
        float* ob = outp + b * 262144 + tile * 8192;
        const float* xr2 = xb + tile * 8192;
        #pragma unroll
        for (int i = 0; i < 2; ++i) {
            f32x4 c = { bor[i], bor[i], bor[i], bor[i] };
            c = MFMA8(ta0, woF[i * 2 + 0], c);
            c = MFMA8(ta1, woF[i * 2 + 1], c);
            #pragma unroll
            for (int r = 0; r < 4; ++r) {
                int off = (rtq * 16 + quad * 4 + r) * 64 + (ct0 + i) * 16 + l;
                ob[off] = c[r] + xr2[off];
            }
        }
    }
}

// ---------------- Fallback (round-3 fused kernel, used if ws too small) ----------------
__global__ __launch_bounds__(512) void k_fused(
    const float* __restrict__ x, const float* __restrict__ Wdw, const float* __restrict__ bdw,
    const float* __restrict__ Wq, const float* __restrict__ bq,
    const float* __restrict__ Wk, const float* __restrict__ bk,
    const float* __restrict__ Wv, const float* __restrict__ bv,
    const float* __restrict__ Wo, const float* __restrict__ bo,
    const float* __restrict__ Bb, const float* __restrict__ stats,
    float* __restrict__ outp)
{
    __shared__ long smem8[6784];
    unsigned char* S = (unsigned char*)smem8;
    unsigned char* Kf = S;
    unsigned char* Vt = S + 18432;
    unsigned char* Y  = S + 35328;
    unsigned char* XS = S + 35328;
    unsigned char* QF = S + 35328 + 4608;
    unsigned char* TS = S + 35328 + 14336;

    const int tg = blockIdx.x, b = blockIdx.y;
    const int t = threadIdx.x, w = t >> 6, lane = t & 63;
    const int quad = lane >> 4, l = lane & 15;
    unsigned char* PS = S + 35328 + 9216 + w * 640;

    const float mu = stats[2 * b], rstd = stats[2 * b + 1];
    const float* xb = x + b * 262144;
    const float SCALE = 0.17677669529663687f;

    long wkF[8], wvF[8];
    #pragma unroll
    for (int e4 = 0; e4 < 4; ++e4)
        #pragma unroll
        for (int st = 0; st < 2; ++st) {
            wkF[e4 * 2 + st] = packrow8(Wk + (e4 * 16 + l) * 64 + st * 32 + quad * 8);
            wvF[e4 * 2 + st] = packrow8(Wv + (e4 * 16 + l) * 64 + st * 32 + quad * 8);
        }
    const int rtq = w >> 1, ct0 = (w & 1) * 2;
    long wqF[4], woF[4];
    #pragma unroll
    for (int i = 0; i < 2; ++i)
        #pragma unroll
        for (int st = 0; st < 2; ++st) {
            wqF[i * 2 + st] = packrow8(Wq + ((ct0 + i) * 16 + l) * 64 + st * 32 + quad * 8);
            woF[i * 2 + st] = packrow8(Wo + ((ct0 + i) * 16 + l) * 64 + st * 32 + quad * 8);
        }
    float bkr[4], bvr[4][4], bqr[2], bor[2];
    #pragma unroll
    for (int e4 = 0; e4 < 4; ++e4) bkr[e4] = bk[e4 * 16 + l];
    #pragma unroll
    for (int d4 = 0; d4 < 4; ++d4)
        #pragma unroll
        for (int r = 0; r < 4; ++r) bvr[d4][r] = bv[d4 * 16 + quad * 4 + r];
    #pragma unroll
    for (int i = 0; i < 2; ++i) { bqr[i] = bq[(ct0 + i) * 16 + l]; bor[i] = bo[(ct0 + i) * 16 + l]; }

    {
        const int s2l = lane & 3, mjl = lane >> 2;
        for (int ci = 0; ci < 8; ++ci) {
            int c = w * 8 + ci;
            float wd0 = Wdw[c * 16 + 0 + s2l];
            float wd1 = Wdw[c * 16 + 4 + s2l];
            float wd2 = Wdw[c * 16 + 8 + s2l];
            float wd3 = Wdw[c * 16 + 12 + s2l];
            float bdc = bdw[c];
            #pragma unroll 4
            for (int mi = 0; mi < 16; ++mi) {
                const float* xr = xb + c * 4096 + mi * 256;
                float acc = xr[lane] * wd0;
                acc = fmaf(xr[64 + lane],  wd1, acc);
                acc = fmaf(xr[128 + lane], wd2, acc);
                acc = fmaf(xr[192 + lane], wd3, acc);
                acc += __shfl_xor(acc, 1);
                acc += __shfl_xor(acc, 2);
                if (s2l == 0) Y[(mi * 16 + mjl) * 72 + c] = f2fp8(acc + bdc);
            }
        }
    }
    __syncthreads();

    #pragma unroll
    for (int i = 0; i < 2; ++i) {
        int rt = w * 2 + i;
        long ya0 = *(const long*)(Y + (rt * 16 + l) * 72 + quad * 8);
        long ya1 = *(const long*)(Y + (rt * 16 + l) * 72 + 32 + quad * 8);
        #pragma unroll
        for (int e4 = 0; e4 < 4; ++e4) {
            f32x4 c = { bkr[e4], bkr[e4], bkr[e4], bkr[e4] };
            c = MFMA8(ya0, wkF[e4 * 2 + 0], c);
            c = MFMA8(ya1, wkF[e4 * 2 + 1], c);
            unsigned char* kd = Kf + (rt * 16 + quad * 4) * 72 + e4 * 16 + l;
            #pragma unroll
            for (int r = 0; r < 4; ++r) kd[r * 72] = f2fp8(c[r]);
        }
        #pragma unroll
        for (int d4 = 0; d4 < 4; ++d4) {
            f32x4 c = { bvr[d4][0], bvr[d4][1], bvr[d4][2], bvr[d4][3] };
            c = MFMA8(wvF[d4 * 2 + 0], ya0, c);
            c = MFMA8(wvF[d4 * 2 + 1], ya1, c);
            unsigned char* vd = Vt + (d4 * 16 + quad * 4) * 264 + rt * 16 + l;
            #pragma unroll
            for (int r = 0; r < 4; ++r) vd[r * 264] = f2fp8(c[r]);
        }
    }
    __syncthreads();

    const int h = w & 1, nq = w >> 1;

    for (int tile = 0; tile < 8; ++tile) {
        const int tidx = tg * 8 + tile, n0 = tidx * 64;

        for (int ci = 0; ci < 8; ++ci) {
            int c = w * 8 + ci;
            float v = (xb[c * 4096 + n0 + lane] - mu) * rstd;
            XS[lane * 72 + c] = f2fp8(v);
        }
        __syncthreads();

        {
            long xa0 = *(const long*)(XS + (rtq * 16 + l) * 72 + quad * 8);
            long xa1 = *(const long*)(XS + (rtq * 16 + l) * 72 + 32 + quad * 8);
            #pragma unroll
            for (int i = 0; i < 2; ++i) {
                f32x4 c = { bqr[i], bqr[i], bqr[i], bqr[i] };
                c = MFMA8(xa0, wqF[i * 2 + 0], c);
                c = MFMA8(xa1, wqF[i * 2 + 1], c);
                unsigned char* qd = QF + (rtq * 16 + quad * 4) * 72 + (ct0 + i) * 16 + l;
                #pragma unroll
                for (int r = 0; r < 4; ++r) qd[r * 72] = f2fp8(c[r]);
            }
        }
        __syncthreads();

        long qa = *(const long*)(QF + (nq * 16 + l) * 72 + h * 32 + quad * 8);
        f32x4 O0 = { 0, 0, 0, 0 }, O1 = { 0, 0, 0, 0 };
        float Lp[4] = { 0, 0, 0, 0 };
        const float* Bbase = Bb + h * 1048576 + (n0 + nq * 16 + quad * 4) * 256;

        #pragma unroll 2
        for (int mc = 0; mc < 8; ++mc) {
            #pragma unroll
            for (int sub = 0; sub < 2; ++sub) {
                int mt = mc * 2 + sub;
                long kb = *(const long*)(Kf + (mt * 16 + l) * 72 + h * 32 + quad * 8);
                f32x4 sc = { 0, 0, 0, 0 };
                sc = MFMA8(qa, kb, sc);
                unsigned char* pw = PS + (quad * 4) * 40 + sub * 16 + l;
                #pragma unroll
                for (int r = 0; r < 4; ++r) {
                    float p = __expf(fmaf(sc[r], SCALE, Bbase[r * 256 + mt * 16 + l]));
                    Lp[r] += p;
                    pw[r * 40] = f2fp8(p);
                }
            }
            long pa  = *(const long*)(PS + l * 40 + quad * 8);
            long vb0 = *(const long*)(Vt + (h * 32 + l) * 264 + mc * 32 + quad * 8);
            long vb1 = *(const long*)(Vt + (h * 32 + 16 + l) * 264 + mc * 32 + quad * 8);
            O0 = MFMA8(pa, vb0, O0);
            O1 = MFMA8(pa, vb1, O1);
        }
        #pragma unroll
        for (int r = 0; r < 4; ++r) {
            #pragma unroll
            for (int d = 1; d < 16; d <<= 1) Lp[r] += __shfl_xor(Lp[r], d);
        }
        {
            unsigned char* td = TS + (nq * 16 + quad * 4) * 72 + h * 32 + l;
            #pragma unroll
            for (int r = 0; r < 4; ++r) {
                float inv = 1.0f / Lp[r];
                td[r * 72]      = f2fp8(O0[r] * inv);
                td[r * 72 + 16] = f2fp8(O1[r] * inv);
            }
        }
        __syncthreads();

        {
            long ta0 = *(const long*)(TS + (rtq * 16 + l) * 72 + quad * 8);
            long ta1 = *(const long*)(TS + (rtq * 16 + l) * 72 + 32 + quad * 8);
            float* ob = outp + b * 262144 + tidx * 4096;
            const float* xr2 = xb + tidx * 4096;
            #pragma unroll
            for (int i = 0; i < 2; ++i) {
                f32x4 c = { bor[i], bor[i], bor[i], bor[i] };
                c = MFMA8(ta0, woF[i * 2 + 0], c);
                c = MFMA8(ta1, woF[i * 2 + 1], c);
                #pragma unroll
                for (int r = 0; r < 4; ++r) {
                    int off = (rtq * 16 + quad * 4 + r) * 64 + (ct0 + i) * 16 + l;
                    ob[off] = c[r] + xr2[off];
                }
            }
        }
        __syncthreads();
    }
}

extern "C" void kernel_launch(void* const* d_in, const int* in_sizes, int n_in,
                              void* d_out, int out_size, void* d_ws, size_t ws_size,
                              hipStream_t stream) {
    (void)in_sizes; (void)n_in; (void)out_size;
    const float* x   = (const float*)d_in[0];
    const float* Wdw = (const float*)d_in[1];
    const float* bdw = (const float*)d_in[2];
    const float* Wq  = (const float*)d_in[3];
    const float* bq  = (const float*)d_in[4];
    const float* Wk  = (const float*)d_in[5];
    const float* bk  = (const float*)d_in[6];
    const float* Wv  = (const float*)d_in[7];
    const float* bv  = (const float*)d_in[8];
    const float* Wo  = (const float*)d_in[9];
    const float* bo  = (const float*)d_in[10];
    const float* Bb  = (const float*)d_in[11];
    float* outp = (float*)d_out;

    float* ws    = (float*)d_ws;
    float* part  = ws;                                     // 1024 f32 @ 0
    float* stats = ws + 1024;                              // 64 f32  @ 4096 (fallback only)
    unsigned char* Wq8 = (unsigned char*)d_ws + 8192;      // 4 KB
    unsigned char* Wo8 = (unsigned char*)d_ws + 12288;     // 4 KB
    unsigned char* Kg  = (unsigned char*)d_ws + 16384;     // 512 KB (swizzled)
    unsigned char* Vg  = Kg + 524288;                      // 512 KB

    if (ws_size >= (size_t)(16384 + 2 * 524288)) {
        k_kvb2<<<dim3(16, 32), 512, 0, stream>>>(x, Wdw, bdw, Wk, bk, Wv, bv, Wq, Wo,
                                                 Kg, Vg, part, Wq8, Wo8);
        k_attn6<<<dim3(32, 32), 1024, 0, stream>>>(x, Wq8, bq, Wo8, bo, Bb, part, Kg, Vg, outp);
    } else {
        k_ln_part<<<dim3(16, 32), 256, 0, stream>>>(x, part);
        k_ln_fin<<<1, 64, 0, stream>>>(part, stats);
        k_fused<<<dim3(8, 32), 512, 0, stream>>>(x, Wdw, bdw, Wq, bq, Wk, bk, Wv, bv,
                                                 Wo, bo, Bb, stats, outp);
    }
}

// Round 9
// 144.375 us; speedup vs baseline: 1.0289x; 1.0289x over previous
//
#include <hip/hip_runtime.h>

typedef float f32x4 __attribute__((ext_vector_type(4)));

#define MFMA8(a, b, c) __builtin_amdgcn_mfma_f32_16x16x32_fp8_fp8((long)(a), (long)(b), (c), 0, 0, 0)

__device__ __forceinline__ unsigned char f2fp8(float v) {
    int pk = __builtin_amdgcn_cvt_pk_fp8_f32(v, v, 0, false);
    return (unsigned char)(pk & 0xff);
}
__device__ __forceinline__ long packrow8(const float* p) {
    f32x4 a = *(const f32x4*)(p);
    f32x4 b = *(const f32x4*)(p + 4);
    int lo = __builtin_amdgcn_cvt_pk_fp8_f32(a.x, a.y, 0, false);
    lo = __builtin_amdgcn_cvt_pk_fp8_f32(a.z, a.w, lo, true);
    int hi = __builtin_amdgcn_cvt_pk_fp8_f32(b.x, b.y, 0, false);
    hi = __builtin_amdgcn_cvt_pk_fp8_f32(b.z, b.w, hi, true);
    return (long)(((unsigned long)(unsigned int)hi << 32) | (unsigned int)lo);
}
__device__ __forceinline__ int pack4(const float* p) {
    int v = __builtin_amdgcn_cvt_pk_fp8_f32(p[0], p[1], 0, false);
    return __builtin_amdgcn_cvt_pk_fp8_f32(p[2], p[3], v, true);
}
// pack 8 register floats -> 8 fp8 bytes (same cvt_pk rounding as f2fp8 path)
__device__ __forceinline__ long pack8v(const float* p) {
    int lo = __builtin_amdgcn_cvt_pk_fp8_f32(p[0], p[1], 0, false);
    lo = __builtin_amdgcn_cvt_pk_fp8_f32(p[2], p[3], lo, true);
    int hi = __builtin_amdgcn_cvt_pk_fp8_f32(p[4], p[5], 0, false);
    hi = __builtin_amdgcn_cvt_pk_fp8_f32(p[6], p[7], hi, true);
    return (long)(((unsigned long)(unsigned int)hi << 32) | (unsigned int)lo);
}

// ---------------- Kernel 1 (fallback only): LayerNorm partial sums ----------------
__global__ __launch_bounds__(256) void k_ln_part(const float* __restrict__ x,
                                                 float* __restrict__ part) {
    const int chunk = blockIdx.x, b = blockIdx.y, t = threadIdx.x;
    const float4* p = (const float4*)(x + b * 262144 + chunk * 16384);
    float s = 0.f, ss = 0.f;
    #pragma unroll
    for (int r = 0; r < 16; ++r) {
        float4 v = p[r * 256 + t];
        s  += v.x + v.y + v.z + v.w;
        ss += v.x * v.x + v.y * v.y + v.z * v.z + v.w * v.w;
    }
    #pragma unroll
    for (int off = 32; off > 0; off >>= 1) {
        s  += __shfl_down(s, off);
        ss += __shfl_down(ss, off);
    }
    __shared__ float sm[8];
    int wv = t >> 6;
    if ((t & 63) == 0) { sm[wv * 2] = s; sm[wv * 2 + 1] = ss; }
    __syncthreads();
    if (t == 0) {
        float S  = sm[0] + sm[2] + sm[4] + sm[6];
        float SS = sm[1] + sm[3] + sm[5] + sm[7];
        part[(b * 16 + chunk) * 2]     = S;
        part[(b * 16 + chunk) * 2 + 1] = SS;
    }
}

// ---------------- Kernel 2 (fallback only): LayerNorm finalize ----------------
__global__ void k_ln_fin(const float* __restrict__ part, float* __restrict__ stats) {
    int t = threadIdx.x;
    if (t < 32) {
        float S = 0.f, SS = 0.f;
        for (int k = 0; k < 16; ++k) {
            S  += part[(t * 16 + k) * 2];
            SS += part[(t * 16 + k) * 2 + 1];
        }
        const float inv = 1.0f / 262144.0f;
        float mu  = S * inv;
        float var = SS * inv - mu * mu;
        stats[t * 2]     = mu;
        stats[t * 2 + 1] = rsqrtf(var + 1e-5f);
    }
}

// ---------------- Kernel A: conv + K/V build + LN partials + weight pack ----------------
// grid (16 mi-rows, 32 batches), 512 threads. K stored [b][m][64] XOR-SWIZZLED
// (col ^= (row&7)<<3, matching k_attn5's reads), V stored [b][d][256].
// r6 (kept): x read as dwordx4 (1024 B/wave/instr); conv = per-lane dot(float4,float4)
// + 2 shuffles (xor16,32). Block (0,0) additionally packs Wq/Wo to fp8.
__global__ __launch_bounds__(512) void k_kvb2(
    const float* __restrict__ x, const float* __restrict__ Wdw, const float* __restrict__ bdw,
    const float* __restrict__ Wk, const float* __restrict__ bk,
    const float* __restrict__ Wv, const float* __restrict__ bv,
    const float* __restrict__ Wq, const float* __restrict__ Wo,
    unsigned char* __restrict__ Kg, unsigned char* __restrict__ Vg,
    float* __restrict__ part, unsigned char* __restrict__ Wq8, unsigned char* __restrict__ Wo8)
{
    __shared__ __align__(16) unsigned char Y[16 * 72];
    __shared__ float sm[16];
    const int mi = blockIdx.x, b = blockIdx.y;
    const int t = threadIdx.x, w = t >> 6, lane = t & 63;
    const int quad = lane >> 4, l = lane & 15;
    const float* xb = x + b * 262144;

    // weight fp8 pre-pack, one block only (512 threads x 8 values each matrix)
    if ((mi | b) == 0) {
        float f[8];
        #pragma unroll
        for (int g = 0; g < 2; ++g) *(f32x4*)&f[g * 4] = *(const f32x4*)(Wq + t * 8 + g * 4);
        int2 o;
        o.x = pack4(f); o.y = pack4(f + 4);
        *(int2*)(Wq8 + t * 8) = o;
        #pragma unroll
        for (int g = 0; g < 2; ++g) *(f32x4*)&f[g * 4] = *(const f32x4*)(Wo + t * 8 + g * 4);
        o.x = pack4(f); o.y = pack4(f + 4);
        *(int2*)(Wo8 + t * 8) = o;
    }

    // lane mapping: r4 = image row within 4-row chunk, c4 = output col (float4 index)
    const int r4 = lane >> 4, c4 = lane & 15;
    float s = 0.f, ss = 0.f;
    #pragma unroll
    for (int ci = 0; ci < 8; ++ci) {
        int c = w * 8 + ci;
        f32x4 wd = *(const f32x4*)(Wdw + c * 16 + r4 * 4);
        f32x4 v  = *(const f32x4*)(xb + c * 4096 + mi * 256 + r4 * 64 + c4 * 4);
        s  += v.x + v.y + v.z + v.w;
        ss += v.x * v.x + v.y * v.y + v.z * v.z + v.w * v.w;
        float acc = v.x * wd.x;
        acc = fmaf(v.y, wd.y, acc);
        acc = fmaf(v.z, wd.z, acc);
        acc = fmaf(v.w, wd.w, acc);
        acc += __shfl_xor(acc, 16);   // sum rows 0<->1 (bit 4 of lane)
        acc += __shfl_xor(acc, 32);   // sum rows 0<->2 (bit 5 of lane)
        if (r4 == 0) Y[c4 * 72 + c] = f2fp8(acc + bdw[c]);
    }
    #pragma unroll
    for (int off = 32; off > 0; off >>= 1) {
        s  += __shfl_down(s, off);
        ss += __shfl_down(ss, off);
    }
    if (lane == 0) { sm[w * 2] = s; sm[w * 2 + 1] = ss; }
    __syncthreads();
    if (t == 0) {
        float S = 0.f, SS = 0.f;
        #pragma unroll
        for (int i = 0; i < 8; ++i) { S += sm[i * 2]; SS += sm[i * 2 + 1]; }
        part[(b * 16 + mi) * 2]     = S;
        part[(b * 16 + mi) * 2 + 1] = SS;
    }

    long ya0 = *(const long*)(Y + l * 72 + quad * 8);
    long ya1 = *(const long*)(Y + l * 72 + 32 + quad * 8);
    if (w < 4) {
        int e4 = w;
        long f0 = packrow8(Wk + (e4 * 16 + l) * 64 + quad * 8);
        long f1 = packrow8(Wk + (e4 * 16 + l) * 64 + 32 + quad * 8);
        float bb = bk[e4 * 16 + l];
        f32x4 c = { bb, bb, bb, bb };
        c = MFMA8(ya0, f0, c);
        c = MFMA8(ya1, f1, c);
        // swizzled K write: row = m-index, col ^= (row&7)<<3  (matches k_attn5 kb reads)
        unsigned char* kdB = Kg + b * 16384;
        int colk = e4 * 16 + l;
        #pragma unroll
        for (int r = 0; r < 4; ++r) {
            int row = mi * 16 + quad * 4 + r;
            kdB[row * 64 + (colk ^ ((row & 7) << 3))] = f2fp8(c[r]);
        }
    } else {
        int d4 = w - 4;
        long f0 = packrow8(Wv + (d4 * 16 + l) * 64 + quad * 8);
        long f1 = packrow8(Wv + (d4 * 16 + l) * 64 + 32 + quad * 8);
        f32x4 c = { bv[d4 * 16 + quad * 4 + 0], bv[d4 * 16 + quad * 4 + 1],
                    bv[d4 * 16 + quad * 4 + 2], bv[d4 * 16 + quad * 4 + 3] };
        c = MFMA8(f0, ya0, c);
        c = MFMA8(f1, ya1, c);
        unsigned char* vd = Vg + b * 16384 + (d4 * 16 + quad * 4) * 256 + mi * 16 + l;
        #pragma unroll
        for (int r = 0; r < 4; ++r) vd[r * 256] = f2fp8(c[r]);
    }
}

// ---------------- Kernel C: per-tile attention (fp8 MFMA), 4 blocks/CU ----------------
// BEST-KNOWN r5 version (143.8 us). 8-wave block, 1 tile/block, proven mc-loop.
// r6 reg-prefetch spilled (+14 us); r8 16-wave widening cost +4 us (barrier domain).
// LDS: Kf 16384 @0 | Vt [64][272] 17408 @16384 | QF/PS/TS 5120 @33792 = 38912 B
// -> 4 blocks/CU (32-wave cap).
__global__ __launch_bounds__(512, 8) void k_attn5(
    const float* __restrict__ x, const unsigned char* __restrict__ Wq8,
    const float* __restrict__ bq, const unsigned char* __restrict__ Wo8,
    const float* __restrict__ bo, const float* __restrict__ Bb,
    const float* __restrict__ part, const unsigned char* __restrict__ Kg,
    const unsigned char* __restrict__ Vg, float* __restrict__ outp)
{
    __shared__ __align__(16) long smem8[4864];   // 38912 B
    unsigned char* S = (unsigned char*)smem8;
    unsigned char* Kf = S;                 // [256][64] swizzled
    unsigned char* Vt = S + 16384;         // [64][272]
    unsigned char* QF = S + 33792;         // [64][72]  (until qa read)
    unsigned char* TS = S + 33792;         // alias (after bar3)
    const int tile = blockIdx.x, b = blockIdx.y;
    const int t = threadIdx.x, w = t >> 6, lane = t & 63;
    const int quad = lane >> 4, l = lane & 15;
    unsigned char* PS = S + 33792 + w * 640;   // alias (mc-loop)
    const int n0 = tile * 64;
    const float* xb = x + b * 262144;
    const float SCALE = 0.17677669529663687f;

    // ---- LN finalize inline (uniform L2 loads) ----
    float Sp = 0.f, SSp = 0.f;
    #pragma unroll
    for (int k2 = 0; k2 < 16; ++k2) {
        Sp  += part[(b * 16 + k2) * 2];
        SSp += part[(b * 16 + k2) * 2 + 1];
    }
    const float invN = 1.0f / 262144.0f;
    const float mu = Sp * invN;
    const float rstd = rsqrtf(SSp * invN - mu * mu + 1e-5f);

    // ---- stage K (identity copy: Kg pre-swizzled) and V (old mapping) ----
    const unsigned char* Kgb = Kg + b * 16384;
    const unsigned char* Vgb = Vg + b * 16384;
    *(uint4*)(Kf + t * 16)        = *(const uint4*)(Kgb + t * 16);
    *(uint4*)(Kf + 8192 + t * 16) = *(const uint4*)(Kgb + 8192 + t * 16);
    #pragma unroll
    for (int r = 0; r < 2; ++r) {
        int idx = t + 512 * r;
        int d = idx >> 4, e16 = (idx & 15) * 16;
        *(uint4*)(Vt + d * 272 + e16) = *(const uint4*)(Vgb + d * 256 + e16);
    }

    // ---- weight fragments from pre-packed fp8 ----
    const int rtq = w >> 1, ct0 = (w & 1) * 2;
    long wqF[4], woF[4];
    float bqr[2], bor[2];
    #pragma unroll
    for (int i = 0; i < 2; ++i) {
        #pragma unroll
        for (int st = 0; st < 2; ++st) {
            wqF[i * 2 + st] = *(const long*)(Wq8 + ((ct0 + i) * 16 + l) * 64 + st * 32 + quad * 8);
            woF[i * 2 + st] = *(const long*)(Wo8 + ((ct0 + i) * 16 + l) * 64 + st * 32 + quad * 8);
        }
        bqr[i] = bq[(ct0 + i) * 16 + l];
        bor[i] = bo[(ct0 + i) * 16 + l];
    }

    // ---- Q A-fragment straight from global x (registers; no XS round trip) ----
    long xa0, xa1;
    {
        const float* xq = xb + n0 + rtq * 16 + l;
        float xn[8];
        #pragma unroll
        for (int j = 0; j < 8; ++j)
            xn[j] = (xq[(quad * 8 + j) * 4096] - mu) * rstd;
        xa0 = pack8v(xn);
        #pragma unroll
        for (int j = 0; j < 8; ++j)
            xn[j] = (xq[(32 + quad * 8 + j) * 4096] - mu) * rstd;
        xa1 = pack8v(xn);
    }
    // ---- Q-gen via MFMA -> QF fp8 (before bar1: overlaps K/V staging latency) ----
    #pragma unroll
    for (int i = 0; i < 2; ++i) {
        f32x4 c = { bqr[i], bqr[i], bqr[i], bqr[i] };
        c = MFMA8(xa0, wqF[i * 2 + 0], c);
        c = MFMA8(xa1, wqF[i * 2 + 1], c);
        unsigned char* qd = QF + (rtq * 16 + quad * 4) * 72 + (ct0 + i) * 16 + l;
        #pragma unroll
        for (int r = 0; r < 4; ++r) qd[r * 72] = f2fp8(c[r]);
    }
    __syncthreads();   // bar1: K/V staged + all QF written

    // ---- attention: wave = (h = w&1, nq = w>>1), 16 q-rows, 256 keys ----
    const int h = w & 1, nq = w >> 1;
    long qa = *(const long*)(QF + (nq * 16 + l) * 72 + h * 32 + quad * 8);
    __syncthreads();   // bar2: qa reads done -> PS may overwrite QF region

    f32x4 O0 = { 0, 0, 0, 0 }, O1 = { 0, 0, 0, 0 };
    float Lp[4] = { 0, 0, 0, 0 };
    const float* Bbase = Bb + h * 1048576 + (n0 + nq * 16 + quad * 4) * 256;

    // kb base: row = mt*16+l (row&7 = l&7), col = (h*32+quad*8) ^ ((l&7)<<3) -- loop-invariant
    const unsigned char* Kfl = Kf + l * 64 + ((h * 32 + quad * 8) ^ ((l & 7) << 3));

    // software-pipelined B loads: Bv holds biases for current mc (PROVEN r0 path)
    float Bv[2][4];
    #pragma unroll
    for (int sub = 0; sub < 2; ++sub)
        #pragma unroll
        for (int r = 0; r < 4; ++r)
            Bv[sub][r] = Bbase[r * 256 + sub * 16 + l];

    #pragma unroll 2
    for (int mc = 0; mc < 8; ++mc) {
        float Bn[2][4];
        if (mc < 7) {
            #pragma unroll
            for (int sub = 0; sub < 2; ++sub)
                #pragma unroll
                for (int r = 0; r < 4; ++r)
                    Bn[sub][r] = Bbase[r * 256 + (mc * 2 + 2 + sub) * 16 + l];
        }
        long kb0 = *(const long*)(Kfl + (mc * 2 + 0) * 1024);
        long kb1 = *(const long*)(Kfl + (mc * 2 + 1) * 1024);
        #pragma unroll
        for (int sub = 0; sub < 2; ++sub) {
            f32x4 sc = { 0, 0, 0, 0 };
            sc = MFMA8(qa, sub ? kb1 : kb0, sc);
            unsigned char* pw = PS + (quad * 4) * 40 + sub * 16 + l;
            #pragma unroll
            for (int r = 0; r < 4; ++r) {
                float p = __expf(fmaf(sc[r], SCALE, Bv[sub][r]));
                Lp[r] += p;
                pw[r * 40] = f2fp8(p);
            }
        }
        long pa  = *(const long*)(PS + l * 40 + quad * 8);
        long vb0 = *(const long*)(Vt + (h * 32 + l) * 272 + mc * 32 + quad * 8);
        long vb1 = *(const long*)(Vt + (h * 32 + 16 + l) * 272 + mc * 32 + quad * 8);
        O0 = MFMA8(pa, vb0, O0);
        O1 = MFMA8(pa, vb1, O1);
        #pragma unroll
        for (int sub = 0; sub < 2; ++sub)
            #pragma unroll
            for (int r = 0; r < 4; ++r)
                Bv[sub][r] = Bn[sub][r];
    }
    #pragma unroll
    for (int r = 0; r < 4; ++r) {
        #pragma unroll
        for (int d = 1; d < 16; d <<= 1) Lp[r] += __shfl_xor(Lp[r], d);
    }
    __syncthreads();   // bar3: all pa reads done -> PS region reusable as TS
    {
        unsigned char* td = TS + (nq * 16 + quad * 4) * 72 + h * 32 + l;
        #pragma unroll
        for (int r = 0; r < 4; ++r) {
            float inv = 1.0f / Lp[r];
            td[r * 72]      = f2fp8(O0[r] * inv);
            td[r * 72 + 16] = f2fp8(O1[r] * inv);
        }
    }
    __syncthreads();   // bar4: TS complete

    // ---- out-proj + bias + residual ----
    {
        long ta0 = *(const long*)(TS + (rtq * 16 + l) * 72 + quad * 8);
        long ta1 = *(const long*)(TS + (rtq * 16 + l) * 72 + 32 + quad * 8);
        float* ob = outp + b * 262144 + tile * 4096;
        const float* xr2 = xb + tile * 4096;
        #pragma unroll
        for (int i = 0; i < 2; ++i) {
            f32x4 c = { bor[i], bor[i], bor[i], bor[i] };
            c = MFMA8(ta0, woF[i * 2 + 0], c);
            c = MFMA8(ta1, woF[i * 2 + 1], c);
            #pragma unroll
            for (int r = 0; r < 4; ++r) {
                int off = (rtq * 16 + quad * 4 + r) * 64 + (ct0 + i) * 16 + l;
                ob[off] = c[r] + xr2[off];
            }
        }
    }
}

// ---------------- Fallback (round-3 fused kernel, used if ws too small) ----------------
__global__ __launch_bounds__(512) void k_fused(
    const float* __restrict__ x, const float* __restrict__ Wdw, const float* __restrict__ bdw,
    const float* __restrict__ Wq, const float* __restrict__ bq,
    const float* __restrict__ Wk, const float* __restrict__ bk,
    const float* __restrict__ Wv, const float* __restrict__ bv,
    const float* __restrict__ Wo, const float* __restrict__ bo,
    const float* __restrict__ Bb, const float* __restrict__ stats,
    float* __restrict__ outp)
{
    __shared__ long smem8[6784];
    unsigned char* S = (unsigned char*)smem8;
    unsigned char* Kf = S;
    unsigned char* Vt = S + 18432;
    unsigned char* Y  = S + 35328;
    unsigned char* XS = S + 35328;
    unsigned char* QF = S + 35328 + 4608;
    unsigned char* TS = S + 35328 + 14336;

    const int tg = blockIdx.x, b = blockIdx.y;
    const int t = threadIdx.x, w = t >> 6, lane = t & 63;
    const int quad = lane >> 4, l = lane & 15;
    unsigned char* PS = S + 35328 + 9216 + w * 640;

    const float mu = stats[2 * b], rstd = stats[2 * b + 1];
    const float* xb = x + b * 262144;
    const float SCALE = 0.17677669529663687f;

    long wkF[8], wvF[8];
    #pragma unroll
    for (int e4 = 0; e4 < 4; ++e4)
        #pragma unroll
        for (int st = 0; st < 2; ++st) {
            wkF[e4 * 2 + st] = packrow8(Wk + (e4 * 16 + l) * 64 + st * 32 + quad * 8);
            wvF[e4 * 2 + st] = packrow8(Wv + (e4 * 16 + l) * 64 + st * 32 + quad * 8);
        }
    const int rtq = w >> 1, ct0 = (w & 1) * 2;
    long wqF[4], woF[4];
    #pragma unroll
    for (int i = 0; i < 2; ++i)
        #pragma unroll
        for (int st = 0; st < 2; ++st) {
            wqF[i * 2 + st] = packrow8(Wq + ((ct0 + i) * 16 + l) * 64 + st * 32 + quad * 8);
            woF[i * 2 + st] = packrow8(Wo + ((ct0 + i) * 16 + l) * 64 + st * 32 + quad * 8);
        }
    float bkr[4], bvr[4][4], bqr[2], bor[2];
    #pragma unroll
    for (int e4 = 0; e4 < 4; ++e4) bkr[e4] = bk[e4 * 16 + l];
    #pragma unroll
    for (int d4 = 0; d4 < 4; ++d4)
        #pragma unroll
        for (int r = 0; r < 4; ++r) bvr[d4][r] = bv[d4 * 16 + quad * 4 + r];
    #pragma unroll
    for (int i = 0; i < 2; ++i) { bqr[i] = bq[(ct0 + i) * 16 + l]; bor[i] = bo[(ct0 + i) * 16 + l]; }

    {
        const int s2l = lane & 3, mjl = lane >> 2;
        for (int ci = 0; ci < 8; ++ci) {
            int c = w * 8 + ci;
            float wd0 = Wdw[c * 16 + 0 + s2l];
            float wd1 = Wdw[c * 16 + 4 + s2l];
            float wd2 = Wdw[c * 16 + 8 + s2l];
            float wd3 = Wdw[c * 16 + 12 + s2l];
            float bdc = bdw[c];
            #pragma unroll 4
            for (int mi = 0; mi < 16; ++mi) {
                const float* xr = xb + c * 4096 + mi * 256;
                float acc = xr[lane] * wd0;
                acc = fmaf(xr[64 + lane],  wd1, acc);
                acc = fmaf(xr[128 + lane], wd2, acc);
                acc = fmaf(xr[192 + lane], wd3, acc);
                acc += __shfl_xor(acc, 1);
                acc += __shfl_xor(acc, 2);
                if (s2l == 0) Y[(mi * 16 + mjl) * 72 + c] = f2fp8(acc + bdc);
            }
        }
    }
    __syncthreads();

    #pragma unroll
    for (int i = 0; i < 2; ++i) {
        int rt = w * 2 + i;
        long ya0 = *(const long*)(Y + (rt * 16 + l) * 72 + quad * 8);
        long ya1 = *(const long*)(Y + (rt * 16 + l) * 72 + 32 + quad * 8);
        #pragma unroll
        for (int e4 = 0; e4 < 4; ++e4) {
            f32x4 c = { bkr[e4], bkr[e4], bkr[e4], bkr[e4] };
            c = MFMA8(ya0, wkF[e4 * 2 + 0], c);
            c = MFMA8(ya1, wkF[e4 * 2 + 1], c);
            unsigned char* kd = Kf + (rt * 16 + quad * 4) * 72 + e4 * 16 + l;
            #pragma unroll
            for (int r = 0; r < 4; ++r) kd[r * 72] = f2fp8(c[r]);
        }
        #pragma unroll
        for (int d4 = 0; d4 < 4; ++d4) {
            f32x4 c = { bvr[d4][0], bvr[d4][1], bvr[d4][2], bvr[d4][3] };
            c = MFMA8(wvF[d4 * 2 + 0], ya0, c);
            c = MFMA8(wvF[d4 * 2 + 1], ya1, c);
            unsigned char* vd = Vt + (d4 * 16 + quad * 4) * 264 + rt * 16 + l;
            #pragma unroll
            for (int r = 0; r < 4; ++r) vd[r * 264] = f2fp8(c[r]);
        }
    }
    __syncthreads();

    const int h = w & 1, nq = w >> 1;

    for (int tile = 0; tile < 8; ++tile) {
        const int tidx = tg * 8 + tile, n0 = tidx * 64;

        for (int ci = 0; ci < 8; ++ci) {
            int c = w * 8 + ci;
            float v = (xb[c * 4096 + n0 + lane] - mu) * rstd;
            XS[lane * 72 + c] = f2fp8(v);
        }
        __syncthreads();

        {
            long xa0 = *(const long*)(XS + (rtq * 16 + l) * 72 + quad * 8);
            long xa1 = *(const long*)(XS + (rtq * 16 + l) * 72 + 32 + quad * 8);
            #pragma unroll
            for (int i = 0; i < 2; ++i) {
                f32x4 c = { bqr[i], bqr[i], bqr[i], bqr[i] };
                c = MFMA8(xa0, wqF[i * 2 + 0], c);
                c = MFMA8(xa1, wqF[i * 2 + 1], c);
                unsigned char* qd = QF + (rtq * 16 + quad * 4) * 72 + (ct0 + i) * 16 + l;
                #pragma unroll
                for (int r = 0; r < 4; ++r) qd[r * 72] = f2fp8(c[r]);
            }
        }
        __syncthreads();

        long qa = *(const long*)(QF + (nq * 16 + l) * 72 + h * 32 + quad * 8);
        f32x4 O0 = { 0, 0, 0, 0 }, O1 = { 0, 0, 0, 0 };
        float Lp[4] = { 0, 0, 0, 0 };
        const float* Bbase = Bb + h * 1048576 + (n0 + nq * 16 + quad * 4) * 256;

        #pragma unroll 2
        for (int mc = 0; mc < 8; ++mc) {
            #pragma unroll
            for (int sub = 0; sub < 2; ++sub) {
                int mt = mc * 2 + sub;
                long kb = *(const long*)(Kf + (mt * 16 + l) * 72 + h * 32 + quad * 8);
                f32x4 sc = { 0, 0, 0, 0 };
                sc = MFMA8(qa, kb, sc);
                unsigned char* pw = PS + (quad * 4) * 40 + sub * 16 + l;
                #pragma unroll
                for (int r = 0; r < 4; ++r) {
                    float p = __expf(fmaf(sc[r], SCALE, Bbase[r * 256 + mt * 16 + l]));
                    Lp[r] += p;
                    pw[r * 40] = f2fp8(p);
                }
            }
            long pa  = *(const long*)(PS + l * 40 + quad * 8);
            long vb0 = *(const long*)(Vt + (h * 32 + l) * 264 + mc * 32 + quad * 8);
            long vb1 = *(const long*)(Vt + (h * 32 + 16 + l) * 264 + mc * 32 + quad * 8);
            O0 = MFMA8(pa, vb0, O0);
            O1 = MFMA8(pa, vb1, O1);
        }
        #pragma unroll
        for (int r = 0; r < 4; ++r) {
            #pragma unroll
            for (int d = 1; d < 16; d <<= 1) Lp[r] += __shfl_xor(Lp[r], d);
        }
        {
            unsigned char* td = TS + (nq * 16 + quad * 4) * 72 + h * 32 + l;
            #pragma unroll
            for (int r = 0; r < 4; ++r) {
                float inv = 1.0f / Lp[r];
                td[r * 72]      = f2fp8(O0[r] * inv);
                td[r * 72 + 16] = f2fp8(O1[r] * inv);
            }
        }
        __syncthreads();

        {
            long ta0 = *(const long*)(TS + (rtq * 16 + l) * 72 + quad * 8);
            long ta1 = *(const long*)(TS + (rtq * 16 + l) * 72 + 32 + quad * 8);
            float* ob = outp + b * 262144 + tidx * 4096;
            const float* xr2 = xb + tidx * 4096;
            #pragma unroll
            for (int i = 0; i < 2; ++i) {
                f32x4 c = { bor[i], bor[i], bor[i], bor[i] };
                c = MFMA8(ta0, woF[i * 2 + 0], c);
                c = MFMA8(ta1, woF[i * 2 + 1], c);
                #pragma unroll
                for (int r = 0; r < 4; ++r) {
                    int off = (rtq * 16 + quad * 4 + r) * 64 + (ct0 + i) * 16 + l;
                    ob[off] = c[r] + xr2[off];
                }
            }
        }
        __syncthreads();
    }
}

extern "C" void kernel_launch(void* const* d_in, const int* in_sizes, int n_in,
                              void* d_out, int out_size, void* d_ws, size_t ws_size,
                              hipStream_t stream) {
    (void)in_sizes; (void)n_in; (void)out_size;
    const float* x   = (const float*)d_in[0];
    const float* Wdw = (const float*)d_in[1];
    const float* bdw = (const float*)d_in[2];
    const float* Wq  = (const float*)d_in[3];
    const float* bq  = (const float*)d_in[4];
    const float* Wk  = (const float*)d_in[5];
    const float* bk  = (const float*)d_in[6];
    const float* Wv  = (const float*)d_in[7];
    const float* bv  = (const float*)d_in[8];
    const float* Wo  = (const float*)d_in[9];
    const float* bo  = (const float*)d_in[10];
    const float* Bb  = (const float*)d_in[11];
    float* outp = (float*)d_out;

    float* ws    = (float*)d_ws;
    float* part  = ws;                                     // 1024 f32 @ 0
    float* stats = ws + 1024;                              // 64 f32  @ 4096 (fallback only)
    unsigned char* Wq8 = (unsigned char*)d_ws + 8192;      // 4 KB
    unsigned char* Wo8 = (unsigned char*)d_ws + 12288;     // 4 KB
    unsigned char* Kg  = (unsigned char*)d_ws + 16384;     // 512 KB (swizzled)
    unsigned char* Vg  = Kg + 524288;                      // 512 KB

    if (ws_size >= (size_t)(16384 + 2 * 524288)) {
        k_kvb2<<<dim3(16, 32), 512, 0, stream>>>(x, Wdw, bdw, Wk, bk, Wv, bv, Wq, Wo,
                                                 Kg, Vg, part, Wq8, Wo8);
        k_attn5<<<dim3(64, 32), 512, 0, stream>>>(x, Wq8, bq, Wo8, bo, Bb, part, Kg, Vg, outp);
    } else {
        k_ln_part<<<dim3(16, 32), 256, 0, stream>>>(x, part);
        k_ln_fin<<<1, 64, 0, stream>>>(part, stats);
        k_fused<<<dim3(8, 32), 512, 0, stream>>>(x, Wdw, bdw, Wq, bq, Wk, bk, Wv, bv,
                                                 Wo, bo, Bb, stats, outp);
    }
}